// Round 4
// baseline (3847.514 us; speedup 1.0000x reference)
//
#include <hip/hip_runtime.h>
#include <math.h>
#include <stdint.h>

// AIS estimator: N=1024 samples, B=128, DIM=DX=64, K=16 anneal steps, 3 leapfrog.
// Round 4 = round 3 resubmitted (GPU broker timeout; kernel never ran).
// RNG: JAX *partitionable* threefry mode (modern default):
//   bits[i] = out0 ^ out1 of threefry2x32(key, (hi=0, lo=i)), i = 64-bit iota.
// (Rounds 1-2 used the legacy split-halves mode -> wrong stream -> absmax 15.5.)
//  - q state in LDS [d][t] (runtime-d indexable, per-thread column, 2-way bank = free)
//  - p, matvec accumulators in registers (all loops touching them fully unrolled)
//  - gradient via A = Wdec Wdec^T:  g = bk*((c - qA) - q) + (1-bk)*(mu - q)
//  - final half-kick of each anneal step skipped: p is fully resampled next step

#define WS_A     0
#define WS_MUT   4096
#define WS_CT    12288
#define WS_XT    20480
#define WS_SLW   28672
#define WS_TOTAL (WS_SLW + 131072)

struct KParams {
  float beta[18];
  float dbeta[17];
  uint32_t fk0[16];
  uint32_t fk1[16];
};

__host__ __device__ static inline void threefry2x32(uint32_t ks0, uint32_t ks1,
                                                    uint32_t x0, uint32_t x1,
                                                    uint32_t& o0, uint32_t& o1) {
  uint32_t ks2 = ks0 ^ ks1 ^ 0x1BD11BDAu;
  x0 += ks0; x1 += ks1;
#define TFR(r) { x0 += x1; x1 = (x1 << (r)) | (x1 >> (32 - (r))); x1 ^= x0; }
  TFR(13) TFR(15) TFR(26) TFR(6)
  x0 += ks1; x1 += ks2 + 1u;
  TFR(17) TFR(29) TFR(16) TFR(24)
  x0 += ks2; x1 += ks0 + 2u;
  TFR(13) TFR(15) TFR(26) TFR(6)
  x0 += ks0; x1 += ks1 + 3u;
  TFR(17) TFR(29) TFR(16) TFR(24)
  x0 += ks1; x1 += ks2 + 4u;
  TFR(13) TFR(15) TFR(26) TFR(6)
  x0 += ks2; x1 += ks0 + 5u;
#undef TFR
  o0 = x0; o1 = x1;
}

__device__ __forceinline__ float u_from_bits(uint32_t bits) {
  const float LO = __uint_as_float(0xBF7FFFFFu);  // nextafter(-1,0) in f32
  float f = __uint_as_float((bits >> 9) | 0x3F800000u) - 1.0f;
  float u = fmaf(f, 2.0f, LO);                    // (hi-lo) rounds to exactly 2.0f
  return fmaxf(LO, u);
}

// XLA ErfInv32 (Giles): w = -log1p(-x^2), two-branch polynomial.
__device__ __forceinline__ float erfinv_f(float x) {
  float w = -log1pf(-x * x);
  float p;
  if (w < 5.0f) {
    w -= 2.5f;
    p = 2.81022636e-08f;
    p = fmaf(p, w, 3.43273939e-07f);
    p = fmaf(p, w, -3.5233877e-06f);
    p = fmaf(p, w, -4.39150654e-06f);
    p = fmaf(p, w, 0.00021858087f);
    p = fmaf(p, w, -0.00125372503f);
    p = fmaf(p, w, -0.00417768164f);
    p = fmaf(p, w, 0.246640727f);
    p = fmaf(p, w, 1.50140941f);
  } else {
    w = sqrtf(w) - 3.0f;
    p = -0.000200214257f;
    p = fmaf(p, w, 0.000100950558f);
    p = fmaf(p, w, 0.00134934322f);
    p = fmaf(p, w, -0.00367342844f);
    p = fmaf(p, w, 0.00573950773f);
    p = fmaf(p, w, -0.0076224613f);
    p = fmaf(p, w, 0.00943887047f);
    p = fmaf(p, w, 1.00167406f);
    p = fmaf(p, w, 2.83297682f);
  }
  return p * x;
}

// ---- setup: A = Wdec Wdec^T, muT[d][b], cT[d][b], xT[e][b]
__global__ void k_setup1(const float* __restrict__ x, const float* __restrict__ Wenc,
                         const float* __restrict__ Wdec, float* __restrict__ ws) {
  int t = blockIdx.x * 256 + threadIdx.x;
  float* A   = ws + WS_A;
  float* muT = ws + WS_MUT;
  float* cT  = ws + WS_CT;
  float* xT  = ws + WS_XT;
  if (t < 4096) {
    int i = t >> 6, j = t & 63;
    float s = 0;
    for (int e = 0; e < 64; ++e) s = fmaf(Wdec[i*64+e], Wdec[j*64+e], s);
    A[t] = s;
  } else if (t < 12288) {
    int u = t - 4096; int d = u >> 7, b = u & 127;
    float s = 0;
    for (int e = 0; e < 64; ++e) s = fmaf(x[b*64+e], Wenc[e*64+d], s);
    muT[u] = s;
  } else if (t < 20480) {
    int u = t - 12288; int d = u >> 7, b = u & 127;
    float s = 0;
    for (int e = 0; e < 64; ++e) s = fmaf(x[b*64+e], Wdec[d*64+e], s);
    cT[u] = s;
  } else if (t < 28672) {
    int u = t - 20480; int e = u >> 7, b = u & 127;
    xT[u] = x[b*64+e];
  }
}

// ---- main: per-thread sample trajectory, explicit leapfrog, 17 w-evals
__global__ __launch_bounds__(256) void k_main(const float* __restrict__ qn,
                                              const float* __restrict__ Wdec,
                                              const float* __restrict__ ws,
                                              float* __restrict__ slw_out,
                                              KParams P) {
  __shared__ float qs[64 * 256];  // [d][t]; strictly per-thread column, no barriers
  const int t = threadIdx.x;
  const int gtid = blockIdx.x * 256 + t;
  const int b = gtid & 127;
  const float* muT = ws + WS_MUT;
  const float* cT  = ws + WS_CT;
  const float* xT  = ws + WS_XT;
  const float4* A4 = (const float4*)(ws + WS_A);
  const float4* W4 = (const float4*)Wdec;
  const uint32_t base = (uint32_t)gtid * 64u;
  float p[64], acc[64];
  float slw = 0.0f;

  auto w_eval = [&]() -> float {
    // r = q W  (acc), then ssq / s_q / s_qm
#pragma unroll
    for (int e = 0; e < 64; ++e) acc[e] = 0.0f;
    for (int d = 0; d < 64; ++d) {
      float qd = qs[d*256 + t];
#pragma unroll
      for (int e4 = 0; e4 < 16; ++e4) {
        float4 w4 = W4[d*16 + e4];
        acc[4*e4+0] = fmaf(qd, w4.x, acc[4*e4+0]);
        acc[4*e4+1] = fmaf(qd, w4.y, acc[4*e4+1]);
        acc[4*e4+2] = fmaf(qd, w4.z, acc[4*e4+2]);
        acc[4*e4+3] = fmaf(qd, w4.w, acc[4*e4+3]);
      }
    }
    float ssq = 0.0f;
#pragma unroll
    for (int e = 0; e < 64; ++e) {
      float dd = xT[e*128 + b] - acc[e];
      ssq = fmaf(dd, dd, ssq);
    }
    float s_q = 0.0f, s_qm = 0.0f;
#pragma unroll
    for (int d = 0; d < 64; ++d) {
      float qd = qs[d*256 + t];
      s_q = fmaf(qd, qd, s_q);
      float dm = qd - muT[d*128 + b];
      s_qm = fmaf(dm, dm, s_qm);
    }
    return -0.5f * (64.0f * 1.8378770664093453f + ssq) - 0.5f * (s_q - s_qm);
  };

  auto kick = [&](float bk, int nk) {
    // tvec = q.A  (acc)
#pragma unroll
    for (int d = 0; d < 64; ++d) acc[d] = 0.0f;
    for (int m = 0; m < 64; ++m) {
      float qm = qs[m*256 + t];
#pragma unroll
      for (int d4 = 0; d4 < 16; ++d4) {
        float4 a4 = A4[m*16 + d4];
        acc[4*d4+0] = fmaf(qm, a4.x, acc[4*d4+0]);
        acc[4*d4+1] = fmaf(qm, a4.y, acc[4*d4+1]);
        acc[4*d4+2] = fmaf(qm, a4.z, acc[4*d4+2]);
        acc[4*d4+3] = fmaf(qm, a4.w, acc[4*d4+3]);
      }
    }
    const float omb = 1.0f - bk;
#pragma unroll
    for (int d = 0; d < 64; ++d) {
      float qd = qs[d*256 + t];
      float glik = (cT[d*128 + b] - acc[d]) - qd;          // (x-qW)W^T - q
      float g = fmaf(bk, glik, omb * (muT[d*128 + b] - qd));
      p[d] = fmaf(0.025f, g, p[d]);                        // 0.5*STEP = 0.025
      if (nk == 2) p[d] = fmaf(0.025f, g, p[d]);           // boundary double half-kick
    }
  };

  auto drift = [&]() {
#pragma unroll
    for (int d = 0; d < 64; ++d) {
      float qd = qs[d*256 + t];
      qs[d*256 + t] = fmaf(0.05f, p[d], qd);               // STEP = 0.05
    }
  };

  // j = 0: q0 = mu + q_noise, incremental weight dbeta[0]*w(q0)
#pragma unroll
  for (int d4 = 0; d4 < 16; ++d4) {
    float4 v = *(const float4*)(qn + (size_t)base + 4*d4);
    qs[(4*d4+0)*256 + t] = muT[(4*d4+0)*128 + b] + v.x;
    qs[(4*d4+1)*256 + t] = muT[(4*d4+1)*128 + b] + v.y;
    qs[(4*d4+2)*256 + t] = muT[(4*d4+2)*128 + b] + v.z;
    qs[(4*d4+3)*256 + t] = muT[(4*d4+3)*128 + b] + v.w;
  }
  slw = fmaf(P.dbeta[0], w_eval(), slw);

  for (int j = 1; j <= 16; ++j) {
    const float bk = P.beta[j];
    const uint32_t k0 = P.fk0[j-1], k1 = P.fk1[j-1];
    // momentum refresh: JAX partitionable threefry — per-element 64b counter
    // (hi=0, lo=idx), 32-bit draw = out0 ^ out1; then XLA uniform->erf_inv.
#pragma unroll
    for (int d = 0; d < 64; ++d) {
      uint32_t idx = base + (uint32_t)d;
      uint32_t o0, o1;
      threefry2x32(k0, k1, 0u, idx, o0, o1);
      p[d] = 1.41421356f * erfinv_f(u_from_bits(o0 ^ o1));
    }
    // leapfrog x3: half-kick, drift, (double half-kick, drift)x2; final half-kick dropped (p dead)
    kick(bk, 1);
    drift();
    kick(bk, 2);
    drift();
    kick(bk, 2);
    drift();
    slw = fmaf(P.dbeta[j], w_eval(), slw);
  }
  slw_out[gtid] = slw;
}

// ---- logsumexp over n per batch column b
__global__ void k_reduce(const float* __restrict__ slw, float* __restrict__ out) {
  __shared__ float red[256];
  int b = blockIdx.x, t = threadIdx.x;
  float v[4];
  float m = -INFINITY;
#pragma unroll
  for (int i = 0; i < 4; ++i) {
    v[i] = slw[(t + 256*i)*128 + b];
    m = fmaxf(m, v[i]);
  }
  red[t] = m; __syncthreads();
  for (int s = 128; s > 0; s >>= 1) {
    if (t < s) red[t] = fmaxf(red[t], red[t+s]);
    __syncthreads();
  }
  m = red[0]; __syncthreads();
  float sum = 0.0f;
#pragma unroll
  for (int i = 0; i < 4; ++i) sum += expf(v[i] - m);
  red[t] = sum; __syncthreads();
  for (int s = 128; s > 0; s >>= 1) {
    if (t < s) red[t] += red[t+s];
    __syncthreads();
  }
  if (t == 0) out[b] = m + logf(red[0]) - 6.93147180559945309f;  // - log(1024)
}

extern "C" void kernel_launch(void* const* d_in, const int* in_sizes, int n_in,
                              void* d_out, int out_size, void* d_ws, size_t ws_size,
                              hipStream_t stream) {
  const float* x    = (const float*)d_in[0];
  const float* Wenc = (const float*)d_in[1];
  const float* Wdec = (const float*)d_in[2];
  const float* qn   = (const float*)d_in[3];
  // d_in[4] (p_noise) is dead: momentum is fully resampled every anneal step.
  float* ws  = (float*)d_ws;
  float* out = (float*)d_out;
  if (ws_size < (size_t)WS_TOTAL * sizeof(float)) return;

  KParams P;
  double bb[18];
  for (int i = 0; i < 18; ++i) {
    double tt = (double)i / 17.0;
    bb[i] = 1.0 / (1.0 + exp(-(8.0 * tt - 4.0)));
  }
  for (int i = 0; i < 18; ++i) P.beta[i] = (float)((bb[i] - bb[0]) / (bb[17] - bb[0]));
  for (int j = 0; j <= 16; ++j) P.dbeta[j] = P.beta[j+1] - P.beta[j];
  for (int k = 1; k <= 16; ++k) {
    uint32_t a, c;
    threefry2x32(0u, 42u, 0u, (uint32_t)k, a, c);  // fold_in(key(42), k)
    P.fk0[k-1] = a; P.fk1[k-1] = c;
  }

  hipLaunchKernelGGL(k_setup1, dim3(112), dim3(256), 0, stream, x, Wenc, Wdec, ws);
  hipLaunchKernelGGL(k_main, dim3(512), dim3(256), 0, stream, qn, Wdec, ws, ws + WS_SLW, P);
  hipLaunchKernelGGL(k_reduce, dim3(128), dim3(256), 0, stream, ws + WS_SLW, out);
}